// Round 13
// baseline (248.670 us; speedup 1.0000x reference)
//
#include <hip/hip_runtime.h>
#include <math.h>

// B=32, HID=4096, NH=32, NKV=8, HS=128, BS=16, MAXS=2048, groups=4

typedef __attribute__((ext_vector_type(8))) short bf16x8;
typedef __attribute__((ext_vector_type(4))) float f32x4;

// ---------------------------------------------------------------------------
// bf16 MFMA GEMM (R12, correct; ~= f32 v1 in speed, kept for headroom).
// One wave per (16x16 C-tile, K=1024 split). C/D mapping m89-verified.
// ---------------------------------------------------------------------------
__device__ __forceinline__ unsigned short f2bf(float f) {
    unsigned int u = __float_as_uint(f);
    return (unsigned short)((u + 0x7FFFu + ((u >> 16) & 1u)) >> 16);
}
__device__ __forceinline__ bf16x8 cvt8(float4 a, float4 b) {
    bf16x8 r;
    r[0] = (short)f2bf(a.x); r[1] = (short)f2bf(a.y);
    r[2] = (short)f2bf(a.z); r[3] = (short)f2bf(a.w);
    r[4] = (short)f2bf(b.x); r[5] = (short)f2bf(b.y);
    r[6] = (short)f2bf(b.z); r[7] = (short)f2bf(b.w);
    return r;
}

__device__ __forceinline__ void mfma_tile(
    const float* __restrict__ xp, const float* __restrict__ wp,
    float* __restrict__ dst, int dstr, int n0, int mh, int lane)
{
    f32x4 acc = {0.f, 0.f, 0.f, 0.f};
#pragma unroll 4
    for (int s = 0; s < 32; ++s) {
        float4 xa = *(const float4*)(xp + s * 32);
        float4 xb = *(const float4*)(xp + s * 32 + 4);
        float4 wa = *(const float4*)(wp + s * 32);
        float4 wb = *(const float4*)(wp + s * 32 + 4);
        acc = __builtin_amdgcn_mfma_f32_16x16x32_bf16(
            cvt8(xa, xb), cvt8(wa, wb), acc, 0, 0, 0);
    }
    int ccol = n0 + (lane & 15);
    int rbase = mh * 16 + ((lane >> 4) << 2);
    atomicAdd(dst + (size_t)(rbase + 0) * dstr + ccol, acc[0]);
    atomicAdd(dst + (size_t)(rbase + 1) * dstr + ccol, acc[1]);
    atomicAdd(dst + (size_t)(rbase + 2) * dstr + ccol, acc[2]);
    atomicAdd(dst + (size_t)(rbase + 3) * dstr + ccol, acc[3]);
}

// grid = 768 blocks x 256 thr = 3072 waves
__global__ __launch_bounds__(256) void qkv_mfma(
    const float* __restrict__ x, const float* __restrict__ wq,
    const float* __restrict__ wk, const float* __restrict__ wv,
    float* __restrict__ qb, float* __restrict__ knb, float* __restrict__ vnb)
{
    int gw = (blockIdx.x << 2) + (threadIdx.x >> 6);
    int lane = threadIdx.x & 63;
    int split = gw & 3;
    int mh = (gw >> 2) & 1;
    int nt = gw >> 3;
    const float* w; float* dst; int dstr; int n0;
    if (nt < 256)      { w = wq; n0 = nt * 16;         dst = qb;  dstr = 4096; }
    else if (nt < 320) { w = wk; n0 = (nt - 256) * 16; dst = knb; dstr = 1024; }
    else               { w = wv; n0 = (nt - 320) * 16; dst = vnb; dstr = 1024; }
    int row = lane & 15, kq = (lane >> 4) << 3;
    int kbase = split << 10;
    const float* xp = x + (size_t)(mh * 16 + row) * 4096 + kbase + kq;
    const float* wp = w + (size_t)(n0 + row) * 4096 + kbase + kq;
    mfma_tile(xp, wp, dst, dstr, n0, mh, lane);
}

// grid = 512 blocks x 256 thr = 2048 waves
__global__ __launch_bounds__(256) void wo_mfma(
    const float* __restrict__ attn, const float* __restrict__ wo,
    float* __restrict__ out)
{
    int gw = (blockIdx.x << 2) + (threadIdx.x >> 6);
    int lane = threadIdx.x & 63;
    int split = gw & 3;
    int mh = (gw >> 2) & 1;
    int nt = gw >> 3;
    int n0 = nt * 16;
    int row = lane & 15, kq = (lane >> 4) << 3;
    int kbase = split << 10;
    const float* xp = attn + (size_t)(mh * 16 + row) * 4096 + kbase + kq;
    const float* wp = wo + (size_t)(n0 + row) * 4096 + kbase + kq;
    mfma_tile(xp, wp, out, 4096, n0, mh, lane);
}

// ---------------------------------------------------------------------------
// RoPE in-place on q (32 heads) and k_new (8 heads). grid = 32*40, block = 64.
// ---------------------------------------------------------------------------
__global__ void rope_kernel(float* __restrict__ qb, float* __restrict__ knb,
                            const int* __restrict__ lens)
{
    int bid = blockIdx.x;
    int b = bid / 40, r = bid % 40;
    float* row = (r < 32) ? (qb + (size_t)b * 4096 + r * 128)
                          : (knb + (size_t)b * 1024 + (r - 32) * 128);
    int d = threadIdx.x;
    float pos = (float)(lens[b] - 1);
    float inv = exp2f(-(float)d * 0.207620505930460f);  // 10000^(-d/64)
    float fr = pos * inv;
    float s, c;
    sincosf(fr, &s, &c);
    float x1 = row[d], x2 = row[d + 64];
    row[d]      = x1 * c - x2 * s;
    row[d + 64] = x2 * c + x1 * s;
}

// ---------------------------------------------------------------------------
// Flash-decode attention v5: DENSE + PARALLEL. One wave per (b, 16-position
// chunk) = exactly one page-table block -> the 16 slots are CONTIGUOUS: each
// wave streams 64KB contiguous K + 64KB contiguous V (4KB full rows, lane
// offset lane*64B). No slot table, no LDS, no barriers, one btab read.
// Lane = (h = lane>>3 kv-head, i = lane&7 -> 16-float dim slice); per
// position: 4 GQA dots x 16 FMA, RED8 (3 shfl), subgroup-local online
// softmax (v4 math, proven correct), PV 64 FMA. 2-deep named-reg prefetch.
// vs v3: fixes the 512B-scatter-at-4KB-stride DRAM pattern. vs v4 (chunk32,
// regressed): 2x the waves (2048 active, 8/CU) restores latency hiding.
// Chunk-major bid for CU balance. Validity via loop bound (no masking).
// ---------------------------------------------------------------------------
#define V4MUL(V, S) { V.x *= S; V.y *= S; V.z *= S; V.w *= S; }
#define V4FMA(O, P, V) { O.x = fmaf(P, V.x, O.x); O.y = fmaf(P, V.y, O.y); \
                         O.z = fmaf(P, V.z, O.z); O.w = fmaf(P, V.w, O.w); }
#define DOT4(S, Q, K) { S = fmaf(Q.x, K.x, S); S = fmaf(Q.y, K.y, S); \
                        S = fmaf(Q.z, K.z, S); S = fmaf(Q.w, K.w, S); }
#define RED8(X) { X += __shfl_xor(X, 1, 64); X += __shfl_xor(X, 2, 64); \
                  X += __shfl_xor(X, 4, 64); }

// load position r_'s row slice (16 K + 16 V floats) into named set S
#define LOADP(S, r_) { \
    const float* kp_ = ((r_) == lastr) ? knew : (kbase + (size_t)(r_) * 1024); \
    const float* vp_ = ((r_) == lastr) ? vnew : (vbase + (size_t)(r_) * 1024); \
    S##k0 = *(const float4*)(kp_);      S##k1 = *(const float4*)(kp_ + 4); \
    S##k2 = *(const float4*)(kp_ + 8);  S##k3 = *(const float4*)(kp_ + 12); \
    S##v0 = *(const float4*)(vp_);      S##v1 = *(const float4*)(vp_ + 4); \
    S##v2 = *(const float4*)(vp_ + 8);  S##v3 = *(const float4*)(vp_ + 12); }

#define OUPD(S, s_, m_, l_, O0_, O1_, O2_, O3_) { \
    if (s_ > m_) { \
        float c_ = __expf(m_ - s_); \
        l_ *= c_; V4MUL(O0_, c_) V4MUL(O1_, c_) V4MUL(O2_, c_) V4MUL(O3_, c_) \
        m_ = s_; \
    } \
    float pe_ = __expf(s_ - m_); \
    l_ += pe_; \
    V4FMA(O0_, pe_, S##v0) V4FMA(O1_, pe_, S##v1) \
    V4FMA(O2_, pe_, S##v2) V4FMA(O3_, pe_, S##v3) }

#define COMP(S) { \
    float s0 = 0.f, s1 = 0.f, s2 = 0.f, s3 = 0.f; \
    DOT4(s0, q00, S##k0) DOT4(s0, q01, S##k1) DOT4(s0, q02, S##k2) DOT4(s0, q03, S##k3) \
    DOT4(s1, q10, S##k0) DOT4(s1, q11, S##k1) DOT4(s1, q12, S##k2) DOT4(s1, q13, S##k3) \
    DOT4(s2, q20, S##k0) DOT4(s2, q21, S##k1) DOT4(s2, q22, S##k2) DOT4(s2, q23, S##k3) \
    DOT4(s3, q30, S##k0) DOT4(s3, q31, S##k1) DOT4(s3, q32, S##k2) DOT4(s3, q33, S##k3) \
    RED8(s0) RED8(s1) RED8(s2) RED8(s3) \
    OUPD(S, s0, m0, l0, o00, o01, o02, o03) \
    OUPD(S, s1, m1, l1, o10, o11, o12, o13) \
    OUPD(S, s2, m2, l2, o20, o21, o22, o23) \
    OUPD(S, s3, m3, l3, o30, o31, o32, o33) }

__global__ __launch_bounds__(64, 1) void attn_kernel(
    const float* __restrict__ kc, const float* __restrict__ vc,
    const float* __restrict__ qb, const float* __restrict__ knb,
    const float* __restrict__ vnb,
    const int* __restrict__ btab, const int* __restrict__ lens,
    float* __restrict__ part)
{
    int bid = blockIdx.x;
    int c = bid >> 5, b = bid & 31;     // chunk-major: CU balance
    int len = lens[b];
    int p0 = c << 4;
    if (p0 >= len) return;
    int pend = min(len - p0, 16);
    int lastr = (len - 1) - p0;         // in [0,pend) only for the last chunk

    int lane = threadIdx.x;
    int h = lane >> 3;            // kv-head 0..7
    int i = lane & 7;             // 16-float dim slice
    int l16 = lane << 4;          // lane offset within a 4KB row

    const float* kbase = kc + (size_t)btab[b * 128 + c] * 16384 + l16;
    const float* vbase = vc + (size_t)btab[b * 128 + c] * 16384 + l16;
    const float* knew  = knb + (size_t)b * 1024 + l16;
    const float* vnew  = vnb + (size_t)b * 1024 + l16;

    // q slices for this kv-head's 4 GQA q-heads, prescaled
    const float scale = 0.08838834764831845f;   // 1/sqrt(128)
    const float* qr = qb + (size_t)b * 4096 + (size_t)h * 512 + (i << 4);
    float4 q00 = *(const float4*)(qr),        q01 = *(const float4*)(qr + 4);
    float4 q02 = *(const float4*)(qr + 8),    q03 = *(const float4*)(qr + 12);
    float4 q10 = *(const float4*)(qr + 128),  q11 = *(const float4*)(qr + 132);
    float4 q12 = *(const float4*)(qr + 136),  q13 = *(const float4*)(qr + 140);
    float4 q20 = *(const float4*)(qr + 256),  q21 = *(const float4*)(qr + 260);
    float4 q22 = *(const float4*)(qr + 264),  q23 = *(const float4*)(qr + 268);
    float4 q30 = *(const float4*)(qr + 384),  q31 = *(const float4*)(qr + 388);
    float4 q32 = *(const float4*)(qr + 392),  q33 = *(const float4*)(qr + 396);
    V4MUL(q00, scale) V4MUL(q01, scale) V4MUL(q02, scale) V4MUL(q03, scale)
    V4MUL(q10, scale) V4MUL(q11, scale) V4MUL(q12, scale) V4MUL(q13, scale)
    V4MUL(q20, scale) V4MUL(q21, scale) V4MUL(q22, scale) V4MUL(q23, scale)
    V4MUL(q30, scale) V4MUL(q31, scale) V4MUL(q32, scale) V4MUL(q33, scale)

    float m0 = -INFINITY, m1 = -INFINITY, m2 = -INFINITY, m3 = -INFINITY;
    float l0 = 0.f, l1 = 0.f, l2 = 0.f, l3 = 0.f;
    float4 o00 = {0,0,0,0}, o01 = {0,0,0,0}, o02 = {0,0,0,0}, o03 = {0,0,0,0};
    float4 o10 = {0,0,0,0}, o11 = {0,0,0,0}, o12 = {0,0,0,0}, o13 = {0,0,0,0};
    float4 o20 = {0,0,0,0}, o21 = {0,0,0,0}, o22 = {0,0,0,0}, o23 = {0,0,0,0};
    float4 o30 = {0,0,0,0}, o31 = {0,0,0,0}, o32 = {0,0,0,0}, o33 = {0,0,0,0};

    float4 ak0, ak1, ak2, ak3, av0, av1, av2, av3;
    float4 bk0, bk1, bk2, bk3, bv0, bv1, bv2, bv3;

    LOADP(a, 0)
    if (1 < pend) LOADP(b, 1)
    for (int r = 0; r < pend; r += 2) {
        COMP(a)
        if (r + 2 < pend) LOADP(a, r + 2)
        if (r + 1 >= pend) break;
        COMP(b)
        if (r + 3 < pend) LOADP(b, r + 3)
    }

    // write partials: per (b,c): 32 q-heads x 132 floats [O[128], m, l, pad2]
    float* pgb = part + (size_t)(b * 128 + c) * 4224;
    int i16 = i << 4;
    float* d0 = pgb + (size_t)(h * 4 + 0) * 132 + i16;
    float* d1 = pgb + (size_t)(h * 4 + 1) * 132 + i16;
    float* d2 = pgb + (size_t)(h * 4 + 2) * 132 + i16;
    float* d3 = pgb + (size_t)(h * 4 + 3) * 132 + i16;
    *(float4*)(d0) = o00; *(float4*)(d0 + 4) = o01; *(float4*)(d0 + 8) = o02; *(float4*)(d0 + 12) = o03;
    *(float4*)(d1) = o10; *(float4*)(d1 + 4) = o11; *(float4*)(d1 + 8) = o12; *(float4*)(d1 + 12) = o13;
    *(float4*)(d2) = o20; *(float4*)(d2 + 4) = o21; *(float4*)(d2 + 8) = o22; *(float4*)(d2 + 12) = o23;
    *(float4*)(d3) = o30; *(float4*)(d3 + 4) = o31; *(float4*)(d3 + 8) = o32; *(float4*)(d3 + 12) = o33;
    if (i == 0) {
        pgb[(h * 4 + 0) * 132 + 128] = m0; pgb[(h * 4 + 0) * 132 + 129] = l0;
        pgb[(h * 4 + 1) * 132 + 128] = m1; pgb[(h * 4 + 1) * 132 + 129] = l1;
        pgb[(h * 4 + 2) * 132 + 128] = m2; pgb[(h * 4 + 2) * 132 + 129] = l2;
        pgb[(h * 4 + 3) * 132 + 128] = m3; pgb[(h * 4 + 3) * 132 + 129] = l3;
    }
}

// grid = 256 (b*8+h), block = 256 (4 q-heads x 64 lanes)
__global__ __launch_bounds__(256) void combine_kernel(
    const float* __restrict__ part, const int* __restrict__ lens,
    float* __restrict__ attn)
{
    int b = blockIdx.x >> 3, h = blockIdx.x & 7;
    int t = threadIdx.x;
    int g = t >> 6, lane = t & 63;
    int len = lens[b];
    int nch = (len + 15) >> 4;          // up to 128 chunks
    const float* base = part + (size_t)b * 128 * 4224 + (size_t)(h * 4 + g) * 132;
    float M = -INFINITY;
    for (int cc = 0; cc < nch; ++cc)
        M = fmaxf(M, base[(size_t)cc * 4224 + 128]);
    float denom = 0.f, a0 = 0.f, a1 = 0.f;
    int d0 = lane << 1;
    for (int cc = 0; cc < nch; ++cc) {
        const float* pg = base + (size_t)cc * 4224;
        float w = __expf(pg[128] - M);
        denom += w * pg[129];
        a0 += w * pg[d0];
        a1 += w * pg[d0 + 1];
    }
    float inv = 1.f / denom;
    float* dst = attn + (size_t)b * 4096 + (size_t)(h * 4 + g) * 128 + d0;
    dst[0] = a0 * inv;
    dst[1] = a1 * inv;
}

// ---------------------------------------------------------------------------
// Workspace (floats): qb[32][4096] @0, knb[32*1024] @131072, vnb @163840,
// attn[32][4096] @196608, part[32*128*4224] @327680 (~69MB; ws is 1GiB)
// ---------------------------------------------------------------------------
extern "C" void kernel_launch(void* const* d_in, const int* in_sizes, int n_in,
                              void* d_out, int out_size, void* d_ws, size_t ws_size,
                              hipStream_t stream)
{
    const float* x   = (const float*)d_in[0];
    const float* wq  = (const float*)d_in[1];
    const float* wk  = (const float*)d_in[2];
    const float* wv  = (const float*)d_in[3];
    const float* wo  = (const float*)d_in[4];
    const float* kc  = (const float*)d_in[5];
    const float* vc  = (const float*)d_in[6];
    const int* btab  = (const int*)d_in[8];
    const int* lens  = (const int*)d_in[10];

    float* qb   = (float*)d_ws;
    float* knb  = qb  + 32 * 4096;
    float* vnb  = knb + 32 * 1024;
    float* attn = vnb + 32 * 1024;
    float* part = attn + 32 * 4096;
    float* outp = (float*)d_out;

    hipMemsetAsync(d_ws, 0, (size_t)(32 * 4096 + 2 * 32 * 1024) * sizeof(float), stream);
    hipMemsetAsync(d_out, 0, (size_t)32 * 4096 * sizeof(float), stream);

    qkv_mfma<<<768, 256, 0, stream>>>(x, wq, wk, wv, qb, knb, vnb);
    rope_kernel<<<32 * 40, 64, 0, stream>>>(qb, knb, lens);
    attn_kernel<<<4096, 64, 0, stream>>>(kc, vc, qb, knb, vnb, btab, lens, part);
    combine_kernel<<<256, 256, 0, stream>>>(part, lens, attn);
    wo_mfma<<<512, 256, 0, stream>>>(attn, wo, outp);
}

// Round 14
// 169.129 us; speedup vs baseline: 1.4703x; 1.4703x over previous
//
#include <hip/hip_runtime.h>
#include <math.h>

// B=32, HID=4096, NH=32, NKV=8, HS=128, BS=16, MAXS=2048, groups=4

typedef __attribute__((ext_vector_type(8))) short bf16x8;
typedef __attribute__((ext_vector_type(4))) float f32x4;

// ---------------------------------------------------------------------------
// Block-reduced bf16 MFMA GEMM. 4 waves/block compute the SAME 16x16 C-tile
// over different K=1024 quarters (R12's verified fragment/mapping), reduce
// via 4KB LDS, plain coalesced stores. No atomics -> no d_out/ws memsets,
// 7 -> 5 dispatches. Memory pattern identical to R12 (proven ~= f32 v1).
// ---------------------------------------------------------------------------
__device__ __forceinline__ unsigned short f2bf(float f) {
    unsigned int u = __float_as_uint(f);
    return (unsigned short)((u + 0x7FFFu + ((u >> 16) & 1u)) >> 16);
}
__device__ __forceinline__ bf16x8 cvt8(float4 a, float4 b) {
    bf16x8 r;
    r[0] = (short)f2bf(a.x); r[1] = (short)f2bf(a.y);
    r[2] = (short)f2bf(a.z); r[3] = (short)f2bf(a.w);
    r[4] = (short)f2bf(b.x); r[5] = (short)f2bf(b.y);
    r[6] = (short)f2bf(b.z); r[7] = (short)f2bf(b.w);
    return r;
}

__device__ __forceinline__ void mfma_block(
    const float* __restrict__ xp, const float* __restrict__ wp,
    float* __restrict__ dst, int dstr, int n0, int mh)
{
    __shared__ float red[4][64][4];
    int wave = threadIdx.x >> 6, lane = threadIdx.x & 63;
    f32x4 acc = {0.f, 0.f, 0.f, 0.f};
#pragma unroll 4
    for (int s = 0; s < 32; ++s) {
        float4 xa = *(const float4*)(xp + s * 32);
        float4 xb = *(const float4*)(xp + s * 32 + 4);
        float4 wa = *(const float4*)(wp + s * 32);
        float4 wb = *(const float4*)(wp + s * 32 + 4);
        acc = __builtin_amdgcn_mfma_f32_16x16x32_bf16(
            cvt8(xa, xb), cvt8(wa, wb), acc, 0, 0, 0);
    }
    red[wave][lane][0] = acc[0];
    red[wave][lane][1] = acc[1];
    red[wave][lane][2] = acc[2];
    red[wave][lane][3] = acc[3];
    __syncthreads();
    if (threadIdx.x < 64) {
        int l = threadIdx.x;
        int ccol = n0 + (l & 15);
        int rbase = mh * 16 + ((l >> 4) << 2);
#pragma unroll
        for (int j = 0; j < 4; ++j) {
            float s = red[0][l][j] + red[1][l][j] + red[2][l][j] + red[3][l][j];
            dst[(size_t)(rbase + j) * dstr + ccol] = s;
        }
    }
}

// grid = 384 tiles x 2 m-halves = 768 blocks x 256 thr (wave = K-quarter)
__global__ __launch_bounds__(256) void qkv_mfma(
    const float* __restrict__ x, const float* __restrict__ wq,
    const float* __restrict__ wk, const float* __restrict__ wv,
    float* __restrict__ qb, float* __restrict__ knb, float* __restrict__ vnb)
{
    int tb = blockIdx.x;
    int mh = tb & 1, nt = tb >> 1;
    int wave = threadIdx.x >> 6, lane = threadIdx.x & 63;
    const float* w; float* dst; int dstr; int n0;
    if (nt < 256)      { w = wq; n0 = nt * 16;         dst = qb;  dstr = 4096; }
    else if (nt < 320) { w = wk; n0 = (nt - 256) * 16; dst = knb; dstr = 1024; }
    else               { w = wv; n0 = (nt - 320) * 16; dst = vnb; dstr = 1024; }
    int row = lane & 15, kq = (lane >> 4) << 3;
    int kbase = wave << 10;
    const float* xp = x + (size_t)(mh * 16 + row) * 4096 + kbase + kq;
    const float* wp = w + (size_t)(n0 + row) * 4096 + kbase + kq;
    mfma_block(xp, wp, dst, dstr, n0, mh);
}

// grid = 256 tiles x 2 m-halves = 512 blocks x 256 thr
__global__ __launch_bounds__(256) void wo_mfma(
    const float* __restrict__ attn, const float* __restrict__ wo,
    float* __restrict__ out)
{
    int tb = blockIdx.x;
    int mh = tb & 1, nt = tb >> 1;
    int wave = threadIdx.x >> 6, lane = threadIdx.x & 63;
    int n0 = nt * 16;
    int row = lane & 15, kq = (lane >> 4) << 3;
    int kbase = wave << 10;
    const float* xp = attn + (size_t)(mh * 16 + row) * 4096 + kbase + kq;
    const float* wp = wo + (size_t)(n0 + row) * 4096 + kbase + kq;
    mfma_block(xp, wp, out, 4096, n0, mh);
}

// ---------------------------------------------------------------------------
// RoPE in-place on q (32 heads) and k_new (8 heads). grid = 32*40, block = 64.
// ---------------------------------------------------------------------------
__global__ void rope_kernel(float* __restrict__ qb, float* __restrict__ knb,
                            const int* __restrict__ lens)
{
    int bid = blockIdx.x;
    int b = bid / 40, r = bid % 40;
    float* row = (r < 32) ? (qb + (size_t)b * 4096 + r * 128)
                          : (knb + (size_t)b * 1024 + (r - 32) * 128);
    int d = threadIdx.x;
    float pos = (float)(lens[b] - 1);
    float inv = exp2f(-(float)d * 0.207620505930460f);  // 10000^(-d/64)
    float fr = pos * inv;
    float s, c;
    sincosf(fr, &s, &c);
    float x1 = row[d], x2 = row[d + 64];
    row[d]      = x1 * c - x2 * s;
    row[d + 64] = x2 * c + x1 * s;
}

// ---------------------------------------------------------------------------
// Flash-decode attention v3 (R10, best measured - UNCHANGED). One wave per
// (b, kv-head, 128-chunk). Subgroup-local online softmax; 3-deep named-reg
// K/V prefetch; zero barriers, zero K/V LDS. (v4/v5 full-row variants
// regressed: access density is NOT the limiter; per-wave fixed overhead is
// what killed them.) All staging regs named scalars (rule #20).
// ---------------------------------------------------------------------------
#define MUL4(V, S) { V.x *= S; V.y *= S; V.z *= S; V.w *= S; }
#define FMA4(O, P, V) { O.x = fmaf(P, V.x, O.x); O.y = fmaf(P, V.y, O.y); \
                        O.z = fmaf(P, V.z, O.z); O.w = fmaf(P, V.w, O.w); }
#define DOT8(S, QA, QB, K0, K1) { \
    S = fmaf(QA.x, K0.x, S); S = fmaf(QA.y, K0.y, S); \
    S = fmaf(QA.z, K0.z, S); S = fmaf(QA.w, K0.w, S); \
    S = fmaf(QB.x, K1.x, S); S = fmaf(QB.y, K1.y, S); \
    S = fmaf(QB.z, K1.z, S); S = fmaf(QB.w, K1.w, S); }
#define RED16(X) { X += __shfl_xor(X, 1, 64); X += __shfl_xor(X, 2, 64); \
                   X += __shfl_xor(X, 4, 64); X += __shfl_xor(X, 8, 64); }
#define REDG_SUM(X) { X += __shfl_xor(X, 16, 64); X += __shfl_xor(X, 32, 64); }
#define REDG_MAX(X) { X = fmaxf(X, __shfl_xor(X, 16, 64)); \
                      X = fmaxf(X, __shfl_xor(X, 32, 64)); }
#define REDG_SUM4(V) { REDG_SUM(V.x) REDG_SUM(V.y) REDG_SUM(V.z) REDG_SUM(V.w) }

#define ALOADR(S, r_) { \
    int sl = ss[((r_) << 2) + g]; \
    const float* kp; const float* vp; \
    if (sl < 0) { kp = knew; vp = vnew; } \
    else { kp = kc + (size_t)sl * 1024 + hoff; vp = vc + (size_t)sl * 1024 + hoff; } \
    S##k0 = *(const float4*)(kp + isl); S##k1 = *(const float4*)(kp + isl + 4); \
    S##v0 = *(const float4*)(vp + isl); S##v1 = *(const float4*)(vp + isl + 4); }

#define OUPD(s_, m_, l_, Oa_, Ob_, V0_, V1_, vld_) { \
    if (s_ > m_) { \
        float c_ = __expf(m_ - s_); \
        l_ *= c_; MUL4(Oa_, c_) MUL4(Ob_, c_) \
        m_ = s_; \
    } \
    float pe_ = vld_ ? __expf(s_ - m_) : 0.f; \
    l_ += pe_; \
    FMA4(Oa_, pe_, V0_) FMA4(Ob_, pe_, V1_) }

#define ACOMP(S, r_) { \
    float s0 = 0.f, s1 = 0.f, s2 = 0.f, s3 = 0.f; \
    DOT8(s0, q0a, q0b, S##k0, S##k1) \
    DOT8(s1, q1a, q1b, S##k0, S##k1) \
    DOT8(s2, q2a, q2b, S##k0, S##k1) \
    DOT8(s3, q3a, q3b, S##k0, S##k1) \
    RED16(s0) RED16(s1) RED16(s2) RED16(s3) \
    int vld = (((r_) << 2) + g) < pend; \
    if (!vld) { s0 = s1 = s2 = s3 = -INFINITY; } \
    OUPD(s0, m0, l0, o0a, o0b, S##v0, S##v1, vld) \
    OUPD(s1, m1, l1, o1a, o1b, S##v0, S##v1, vld) \
    OUPD(s2, m2, l2, o2a, o2b, S##v0, S##v1, vld) \
    OUPD(s3, m3, l3, o3a, o3b, S##v0, S##v1, vld) }

__global__ __launch_bounds__(64, 1) void attn_kernel(
    const float* __restrict__ kc, const float* __restrict__ vc,
    const float* __restrict__ qb, const float* __restrict__ knb,
    const float* __restrict__ vnb,
    const int* __restrict__ btab, const int* __restrict__ lens,
    float* __restrict__ part)
{
    int bid = blockIdx.x;
    int c = bid & 15, h = (bid >> 4) & 7, b = bid >> 7;
    int len = lens[b];
    int p0 = c << 7;
    if (p0 >= len) return;
    int pend = min(len - p0, 128);
    int nr = (pend + 3) >> 2;     // rounds of 4 positions
    int last = len - 1;

    __shared__ int ss[128];       // slot table; -1 => new k/v row (wave-private)

    int lane = threadIdx.x;
    int g = lane >> 4;            // position-in-round 0..3
    int isl = (lane & 15) << 3;   // dim slice base 0,8,...,120
    int hoff = h * 128;

    {   // slot table: each lane fills 2 consecutive entries (same btab word)
        int idx = lane << 1;
        int p = p0 + idx;
        int bt = btab[b * 128 + (p >> 4)];
        int base = bt * 16 + (p & 15);
        ss[idx]     = (p     == last) ? -1 : base;
        ss[idx + 1] = (p + 1 == last) ? -1 : base + 1;
    }

    const float* knew = knb + ((size_t)b * 8 + h) * 128;
    const float* vnew = vnb + ((size_t)b * 8 + h) * 128;

    const float scale = 0.08838834764831845f;   // 1/sqrt(128)
    const float* qrow = qb + (size_t)b * 4096 + (size_t)h * 512;
    float4 q0a = *(const float4*)(qrow + isl),       q0b = *(const float4*)(qrow + isl + 4);
    float4 q1a = *(const float4*)(qrow + 128 + isl), q1b = *(const float4*)(qrow + 128 + isl + 4);
    float4 q2a = *(const float4*)(qrow + 256 + isl), q2b = *(const float4*)(qrow + 256 + isl + 4);
    float4 q3a = *(const float4*)(qrow + 384 + isl), q3b = *(const float4*)(qrow + 384 + isl + 4);
    MUL4(q0a, scale) MUL4(q0b, scale) MUL4(q1a, scale) MUL4(q1b, scale)
    MUL4(q2a, scale) MUL4(q2b, scale) MUL4(q3a, scale) MUL4(q3b, scale)

    float m0 = -INFINITY, m1 = -INFINITY, m2 = -INFINITY, m3 = -INFINITY;
    float l0 = 0.f, l1 = 0.f, l2 = 0.f, l3 = 0.f;
    float4 o0a = {0,0,0,0}, o0b = {0,0,0,0}, o1a = {0,0,0,0}, o1b = {0,0,0,0};
    float4 o2a = {0,0,0,0}, o2b = {0,0,0,0}, o3a = {0,0,0,0}, o3b = {0,0,0,0};

    float4 ak0, ak1, av0, av1;
    float4 bk0, bk1, bv0, bv1;
    float4 ck0, ck1, cv0, cv1;
    ALOADR(a, 0)
    if (1 < nr) ALOADR(b, 1)
    if (2 < nr) ALOADR(c, 2)
    for (int r = 0; r < nr; r += 3) {
        ACOMP(a, r)
        if (r + 3 < nr) ALOADR(a, r + 3)
        if (r + 1 >= nr) break;
        ACOMP(b, r + 1)
        if (r + 4 < nr) ALOADR(b, r + 4)
        if (r + 2 >= nr) break;
        ACOMP(c, r + 2)
        if (r + 5 < nr) ALOADR(c, r + 5)
    }

    // merge the 4 subgroup partial softmaxes (once per wave)
    float M0 = m0, M1 = m1, M2 = m2, M3 = m3;
    REDG_MAX(M0) REDG_MAX(M1) REDG_MAX(M2) REDG_MAX(M3)
    float w0 = __expf(m0 - M0), w1 = __expf(m1 - M1);
    float w2 = __expf(m2 - M2), w3 = __expf(m3 - M3);
    float L0 = w0 * l0, L1 = w1 * l1, L2 = w2 * l2, L3 = w3 * l3;
    REDG_SUM(L0) REDG_SUM(L1) REDG_SUM(L2) REDG_SUM(L3)
    MUL4(o0a, w0) MUL4(o0b, w0) MUL4(o1a, w1) MUL4(o1b, w1)
    MUL4(o2a, w2) MUL4(o2b, w2) MUL4(o3a, w3) MUL4(o3b, w3)
    REDG_SUM4(o0a) REDG_SUM4(o0b) REDG_SUM4(o1a) REDG_SUM4(o1b)
    REDG_SUM4(o2a) REDG_SUM4(o2b) REDG_SUM4(o3a) REDG_SUM4(o3b)

    // partial layout: per (b,h,c): 4 heads x 132 floats [O[128], m, l, pad2]
    float* pgb = part + (size_t)(((b * 8 + h) * 16 + c) * 4) * 132;
    if (lane < 16) {
        *(float4*)(pgb +       isl) = o0a; *(float4*)(pgb +       isl + 4) = o0b;
        *(float4*)(pgb + 132 + isl) = o1a; *(float4*)(pgb + 132 + isl + 4) = o1b;
        *(float4*)(pgb + 264 + isl) = o2a; *(float4*)(pgb + 264 + isl + 4) = o2b;
        *(float4*)(pgb + 396 + isl) = o3a; *(float4*)(pgb + 396 + isl + 4) = o3b;
    }
    if (lane == 0) {
        pgb[128] = M0; pgb[129] = L0;
        pgb[260] = M1; pgb[261] = L1;
        pgb[392] = M2; pgb[393] = L2;
        pgb[524] = M3; pgb[525] = L3;
    }
}

// grid = 256 (b*8+h), block = 256 (4 heads x 64 lanes)
__global__ __launch_bounds__(256) void combine_kernel(
    const float* __restrict__ part, const int* __restrict__ lens,
    float* __restrict__ attn)
{
    int b = blockIdx.x >> 3, h = blockIdx.x & 7;
    int t = threadIdx.x;
    int g = t >> 6, lane = t & 63;
    int len = lens[b];
    int nch = (len + 127) >> 7;
    const float* base = part + (size_t)(b * 8 + h) * 8448 + (size_t)g * 132;
    float M = -INFINITY;
    for (int cc = 0; cc < nch; ++cc)
        M = fmaxf(M, base[(size_t)cc * 528 + 128]);
    float denom = 0.f, a0 = 0.f, a1 = 0.f;
    int d0 = lane << 1;
    for (int cc = 0; cc < nch; ++cc) {
        const float* pg = base + (size_t)cc * 528;
        float w = __expf(pg[128] - M);
        denom += w * pg[129];
        a0 += w * pg[d0];
        a1 += w * pg[d0 + 1];
    }
    float inv = 1.f / denom;
    float* dst = attn + (size_t)b * 4096 + (size_t)(h * 4 + g) * 128 + d0;
    dst[0] = a0 * inv;
    dst[1] = a1 * inv;
}

// ---------------------------------------------------------------------------
// Workspace (floats): qb[32][4096] @0, knb[32*1024] @131072, vnb @163840,
// attn[32][4096] @196608, part[32*8*16*4*132] @327680 (~8.7MB).
// NO memsets needed: all outputs fully written (no atomics anywhere).
// ---------------------------------------------------------------------------
extern "C" void kernel_launch(void* const* d_in, const int* in_sizes, int n_in,
                              void* d_out, int out_size, void* d_ws, size_t ws_size,
                              hipStream_t stream)
{
    const float* x   = (const float*)d_in[0];
    const float* wq  = (const float*)d_in[1];
    const float* wk  = (const float*)d_in[2];
    const float* wv  = (const float*)d_in[3];
    const float* wo  = (const float*)d_in[4];
    const float* kc  = (const float*)d_in[5];
    const float* vc  = (const float*)d_in[6];
    const int* btab  = (const int*)d_in[8];
    const int* lens  = (const int*)d_in[10];

    float* qb   = (float*)d_ws;
    float* knb  = qb  + 32 * 4096;
    float* vnb  = knb + 32 * 1024;
    float* attn = vnb + 32 * 1024;
    float* part = attn + 32 * 4096;
    float* outp = (float*)d_out;

    qkv_mfma<<<768, 256, 0, stream>>>(x, wq, wk, wv, qb, knb, vnb);
    rope_kernel<<<32 * 40, 64, 0, stream>>>(qb, knb, lens);
    attn_kernel<<<4096, 64, 0, stream>>>(kc, vc, qb, knb, vnb, btab, lens, part);
    combine_kernel<<<256, 256, 0, stream>>>(part, lens, attn);
    wo_mfma<<<512, 256, 0, stream>>>(attn, wo, outp);
}

// Round 15
// 164.475 us; speedup vs baseline: 1.5119x; 1.0283x over previous
//
#include <hip/hip_runtime.h>
#include <math.h>

// B=32, HID=4096, NH=32, NKV=8, HS=128, BS=16, MAXS=2048, groups=4

typedef __attribute__((ext_vector_type(8))) short bf16x8;
typedef __attribute__((ext_vector_type(4))) float f32x4;

// ---------------------------------------------------------------------------
// Block-reduced bf16 MFMA GEMM (R14, proven -9us). 4 waves/block, same 16x16
// C-tile over K=1024 quarters, LDS reduce, coalesced stores, no atomics.
// ---------------------------------------------------------------------------
__device__ __forceinline__ unsigned short f2bf(float f) {
    unsigned int u = __float_as_uint(f);
    return (unsigned short)((u + 0x7FFFu + ((u >> 16) & 1u)) >> 16);
}
__device__ __forceinline__ bf16x8 cvt8(float4 a, float4 b) {
    bf16x8 r;
    r[0] = (short)f2bf(a.x); r[1] = (short)f2bf(a.y);
    r[2] = (short)f2bf(a.z); r[3] = (short)f2bf(a.w);
    r[4] = (short)f2bf(b.x); r[5] = (short)f2bf(b.y);
    r[6] = (short)f2bf(b.z); r[7] = (short)f2bf(b.w);
    return r;
}

__device__ __forceinline__ void mfma_block(
    const float* __restrict__ xp, const float* __restrict__ wp,
    float* __restrict__ dst, int dstr, int n0, int mh)
{
    __shared__ float red[4][64][4];
    int wave = threadIdx.x >> 6, lane = threadIdx.x & 63;
    f32x4 acc = {0.f, 0.f, 0.f, 0.f};
#pragma unroll 4
    for (int s = 0; s < 32; ++s) {
        float4 xa = *(const float4*)(xp + s * 32);
        float4 xb = *(const float4*)(xp + s * 32 + 4);
        float4 wa = *(const float4*)(wp + s * 32);
        float4 wb = *(const float4*)(wp + s * 32 + 4);
        acc = __builtin_amdgcn_mfma_f32_16x16x32_bf16(
            cvt8(xa, xb), cvt8(wa, wb), acc, 0, 0, 0);
    }
    red[wave][lane][0] = acc[0];
    red[wave][lane][1] = acc[1];
    red[wave][lane][2] = acc[2];
    red[wave][lane][3] = acc[3];
    __syncthreads();
    if (threadIdx.x < 64) {
        int l = threadIdx.x;
        int ccol = n0 + (l & 15);
        int rbase = mh * 16 + ((l >> 4) << 2);
#pragma unroll
        for (int j = 0; j < 4; ++j) {
            float s = red[0][l][j] + red[1][l][j] + red[2][l][j] + red[3][l][j];
            dst[(size_t)(rbase + j) * dstr + ccol] = s;
        }
    }
}

// grid = 384 tiles x 2 m-halves = 768 blocks x 256 thr (wave = K-quarter)
__global__ __launch_bounds__(256) void qkv_mfma(
    const float* __restrict__ x, const float* __restrict__ wq,
    const float* __restrict__ wk, const float* __restrict__ wv,
    float* __restrict__ qb, float* __restrict__ knb, float* __restrict__ vnb)
{
    int tb = blockIdx.x;
    int mh = tb & 1, nt = tb >> 1;
    int wave = threadIdx.x >> 6, lane = threadIdx.x & 63;
    const float* w; float* dst; int dstr; int n0;
    if (nt < 256)      { w = wq; n0 = nt * 16;         dst = qb;  dstr = 4096; }
    else if (nt < 320) { w = wk; n0 = (nt - 256) * 16; dst = knb; dstr = 1024; }
    else               { w = wv; n0 = (nt - 320) * 16; dst = vnb; dstr = 1024; }
    int row = lane & 15, kq = (lane >> 4) << 3;
    int kbase = wave << 10;
    const float* xp = x + (size_t)(mh * 16 + row) * 4096 + kbase + kq;
    const float* wp = w + (size_t)(n0 + row) * 4096 + kbase + kq;
    mfma_block(xp, wp, dst, dstr, n0, mh);
}

// grid = 256 tiles x 2 m-halves = 512 blocks x 256 thr
__global__ __launch_bounds__(256) void wo_mfma(
    const float* __restrict__ attn, const float* __restrict__ wo,
    float* __restrict__ out)
{
    int tb = blockIdx.x;
    int mh = tb & 1, nt = tb >> 1;
    int wave = threadIdx.x >> 6, lane = threadIdx.x & 63;
    int n0 = nt * 16;
    int row = lane & 15, kq = (lane >> 4) << 3;
    int kbase = wave << 10;
    const float* xp = attn + (size_t)(mh * 16 + row) * 4096 + kbase + kq;
    const float* wp = wo + (size_t)(n0 + row) * 4096 + kbase + kq;
    mfma_block(xp, wp, out, 4096, n0, mh);
}

// ---------------------------------------------------------------------------
// RoPE in-place on q (32 heads) and k_new (8 heads). grid = 32*40, block = 64.
// ---------------------------------------------------------------------------
__global__ void rope_kernel(float* __restrict__ qb, float* __restrict__ knb,
                            const int* __restrict__ lens)
{
    int bid = blockIdx.x;
    int b = bid / 40, r = bid % 40;
    float* row = (r < 32) ? (qb + (size_t)b * 4096 + r * 128)
                          : (knb + (size_t)b * 1024 + (r - 32) * 128);
    int d = threadIdx.x;
    float pos = (float)(lens[b] - 1);
    float inv = exp2f(-(float)d * 0.207620505930460f);  // 10000^(-d/64)
    float fr = pos * inv;
    float s, c;
    sincosf(fr, &s, &c);
    float x1 = row[d], x2 = row[d + 64];
    row[d]      = x1 * c - x2 * s;
    row[d + 64] = x2 * c + x1 * s;
}

// ---------------------------------------------------------------------------
// Flash-decode attention v6: v3's per-wave body, but the 8 kv-head waves of
// the same (b, 128-chunk) share ONE 512-thread block (wave index = kv-head).
// Same CU + near-lockstep execution -> each round the block touches 4 full
// 4KB KV rows (16KB dense) within a short window -> DRAM row-buffer locality
// (v3's isolated 512B touches at 4KB stride across XCDs were the ~45%-
// efficiency pattern). No in-loop barriers (waves independent); single
// __syncthreads after the shared slot-table fill. Per-wave math identical
// to v3 (best measured). All staging regs named scalars (rule #20).
// ---------------------------------------------------------------------------
#define MUL4(V, S) { V.x *= S; V.y *= S; V.z *= S; V.w *= S; }
#define FMA4(O, P, V) { O.x = fmaf(P, V.x, O.x); O.y = fmaf(P, V.y, O.y); \
                        O.z = fmaf(P, V.z, O.z); O.w = fmaf(P, V.w, O.w); }
#define DOT8(S, QA, QB, K0, K1) { \
    S = fmaf(QA.x, K0.x, S); S = fmaf(QA.y, K0.y, S); \
    S = fmaf(QA.z, K0.z, S); S = fmaf(QA.w, K0.w, S); \
    S = fmaf(QB.x, K1.x, S); S = fmaf(QB.y, K1.y, S); \
    S = fmaf(QB.z, K1.z, S); S = fmaf(QB.w, K1.w, S); }
#define RED16(X) { X += __shfl_xor(X, 1, 64); X += __shfl_xor(X, 2, 64); \
                   X += __shfl_xor(X, 4, 64); X += __shfl_xor(X, 8, 64); }
#define REDG_SUM(X) { X += __shfl_xor(X, 16, 64); X += __shfl_xor(X, 32, 64); }
#define REDG_MAX(X) { X = fmaxf(X, __shfl_xor(X, 16, 64)); \
                      X = fmaxf(X, __shfl_xor(X, 32, 64)); }
#define REDG_SUM4(V) { REDG_SUM(V.x) REDG_SUM(V.y) REDG_SUM(V.z) REDG_SUM(V.w) }

#define ALOADR(S, r_) { \
    int sl = ss[((r_) << 2) + g]; \
    const float* kp; const float* vp; \
    if (sl < 0) { kp = knew; vp = vnew; } \
    else { kp = kc + (size_t)sl * 1024 + hoff; vp = vc + (size_t)sl * 1024 + hoff; } \
    S##k0 = *(const float4*)(kp + isl); S##k1 = *(const float4*)(kp + isl + 4); \
    S##v0 = *(const float4*)(vp + isl); S##v1 = *(const float4*)(vp + isl + 4); }

#define OUPD(s_, m_, l_, Oa_, Ob_, V0_, V1_, vld_) { \
    if (s_ > m_) { \
        float c_ = __expf(m_ - s_); \
        l_ *= c_; MUL4(Oa_, c_) MUL4(Ob_, c_) \
        m_ = s_; \
    } \
    float pe_ = vld_ ? __expf(s_ - m_) : 0.f; \
    l_ += pe_; \
    FMA4(Oa_, pe_, V0_) FMA4(Ob_, pe_, V1_) }

#define ACOMP(S, r_) { \
    float s0 = 0.f, s1 = 0.f, s2 = 0.f, s3 = 0.f; \
    DOT8(s0, q0a, q0b, S##k0, S##k1) \
    DOT8(s1, q1a, q1b, S##k0, S##k1) \
    DOT8(s2, q2a, q2b, S##k0, S##k1) \
    DOT8(s3, q3a, q3b, S##k0, S##k1) \
    RED16(s0) RED16(s1) RED16(s2) RED16(s3) \
    int vld = (((r_) << 2) + g) < pend; \
    if (!vld) { s0 = s1 = s2 = s3 = -INFINITY; } \
    OUPD(s0, m0, l0, o0a, o0b, S##v0, S##v1, vld) \
    OUPD(s1, m1, l1, o1a, o1b, S##v0, S##v1, vld) \
    OUPD(s2, m2, l2, o2a, o2b, S##v0, S##v1, vld) \
    OUPD(s3, m3, l3, o3a, o3b, S##v0, S##v1, vld) }

__global__ __launch_bounds__(512, 1) void attn_kernel(
    const float* __restrict__ kc, const float* __restrict__ vc,
    const float* __restrict__ qb, const float* __restrict__ knb,
    const float* __restrict__ vnb,
    const int* __restrict__ btab, const int* __restrict__ lens,
    float* __restrict__ part)
{
    int bid = blockIdx.x;
    int c = bid >> 5, b = bid & 31;     // chunk-major for CU balance
    int len = lens[b];
    int p0 = c << 7;
    if (p0 >= len) return;
    int pend = min(len - p0, 128);
    int nr = (pend + 3) >> 2;     // rounds of 4 positions
    int last = len - 1;

    __shared__ int ss[128];       // slot table; -1 => new k/v row (block-shared)

    int t = threadIdx.x;
    int h = t >> 6;               // wave = kv-head 0..7
    int lane = t & 63;
    int g = lane >> 4;            // position-in-round 0..3
    int isl = (lane & 15) << 3;   // dim slice base 0,8,...,120
    int hoff = h * 128;

    if (t < 64) {                 // one copy; 2 entries per thread
        int idx = t << 1;
        int p = p0 + idx;
        int bt = btab[b * 128 + (p >> 4)];
        int base = bt * 16 + (p & 15);
        ss[idx]     = (p     == last) ? -1 : base;
        ss[idx + 1] = (p + 1 == last) ? -1 : base + 1;
    }
    __syncthreads();

    const float* knew = knb + ((size_t)b * 8 + h) * 128;
    const float* vnew = vnb + ((size_t)b * 8 + h) * 128;

    const float scale = 0.08838834764831845f;   // 1/sqrt(128)
    const float* qrow = qb + (size_t)b * 4096 + (size_t)h * 512;
    float4 q0a = *(const float4*)(qrow + isl),       q0b = *(const float4*)(qrow + isl + 4);
    float4 q1a = *(const float4*)(qrow + 128 + isl), q1b = *(const float4*)(qrow + 128 + isl + 4);
    float4 q2a = *(const float4*)(qrow + 256 + isl), q2b = *(const float4*)(qrow + 256 + isl + 4);
    float4 q3a = *(const float4*)(qrow + 384 + isl), q3b = *(const float4*)(qrow + 384 + isl + 4);
    MUL4(q0a, scale) MUL4(q0b, scale) MUL4(q1a, scale) MUL4(q1b, scale)
    MUL4(q2a, scale) MUL4(q2b, scale) MUL4(q3a, scale) MUL4(q3b, scale)

    float m0 = -INFINITY, m1 = -INFINITY, m2 = -INFINITY, m3 = -INFINITY;
    float l0 = 0.f, l1 = 0.f, l2 = 0.f, l3 = 0.f;
    float4 o0a = {0,0,0,0}, o0b = {0,0,0,0}, o1a = {0,0,0,0}, o1b = {0,0,0,0};
    float4 o2a = {0,0,0,0}, o2b = {0,0,0,0}, o3a = {0,0,0,0}, o3b = {0,0,0,0};

    float4 ak0, ak1, av0, av1;
    float4 bk0, bk1, bv0, bv1;
    float4 ck0, ck1, cv0, cv1;
    ALOADR(a, 0)
    if (1 < nr) ALOADR(b, 1)
    if (2 < nr) ALOADR(c, 2)
    for (int r = 0; r < nr; r += 3) {
        ACOMP(a, r)
        if (r + 3 < nr) ALOADR(a, r + 3)
        if (r + 1 >= nr) break;
        ACOMP(b, r + 1)
        if (r + 4 < nr) ALOADR(b, r + 4)
        if (r + 2 >= nr) break;
        ACOMP(c, r + 2)
        if (r + 5 < nr) ALOADR(c, r + 5)
    }

    // merge the 4 subgroup partial softmaxes (once per wave)
    float M0 = m0, M1 = m1, M2 = m2, M3 = m3;
    REDG_MAX(M0) REDG_MAX(M1) REDG_MAX(M2) REDG_MAX(M3)
    float w0 = __expf(m0 - M0), w1 = __expf(m1 - M1);
    float w2 = __expf(m2 - M2), w3 = __expf(m3 - M3);
    float L0 = w0 * l0, L1 = w1 * l1, L2 = w2 * l2, L3 = w3 * l3;
    REDG_SUM(L0) REDG_SUM(L1) REDG_SUM(L2) REDG_SUM(L3)
    MUL4(o0a, w0) MUL4(o0b, w0) MUL4(o1a, w1) MUL4(o1b, w1)
    MUL4(o2a, w2) MUL4(o2b, w2) MUL4(o3a, w3) MUL4(o3b, w3)
    REDG_SUM4(o0a) REDG_SUM4(o0b) REDG_SUM4(o1a) REDG_SUM4(o1b)
    REDG_SUM4(o2a) REDG_SUM4(o2b) REDG_SUM4(o3a) REDG_SUM4(o3b)

    // partial layout: per (b,h,c): 4 heads x 132 floats [O[128], m, l, pad2]
    float* pgb = part + (size_t)(((b * 8 + h) * 16 + c) * 4) * 132;
    if (lane < 16) {
        *(float4*)(pgb +       isl) = o0a; *(float4*)(pgb +       isl + 4) = o0b;
        *(float4*)(pgb + 132 + isl) = o1a; *(float4*)(pgb + 132 + isl + 4) = o1b;
        *(float4*)(pgb + 264 + isl) = o2a; *(float4*)(pgb + 264 + isl + 4) = o2b;
        *(float4*)(pgb + 396 + isl) = o3a; *(float4*)(pgb + 396 + isl + 4) = o3b;
    }
    if (lane == 0) {
        pgb[128] = M0; pgb[129] = L0;
        pgb[260] = M1; pgb[261] = L1;
        pgb[392] = M2; pgb[393] = L2;
        pgb[524] = M3; pgb[525] = L3;
    }
}

// grid = 256 (b*8+h), block = 256 (4 heads x 64 lanes)
__global__ __launch_bounds__(256) void combine_kernel(
    const float* __restrict__ part, const int* __restrict__ lens,
    float* __restrict__ attn)
{
    int b = blockIdx.x >> 3, h = blockIdx.x & 7;
    int t = threadIdx.x;
    int g = t >> 6, lane = t & 63;
    int len = lens[b];
    int nch = (len + 127) >> 7;
    const float* base = part + (size_t)(b * 8 + h) * 8448 + (size_t)g * 132;
    float M = -INFINITY;
    for (int cc = 0; cc < nch; ++cc)
        M = fmaxf(M, base[(size_t)cc * 528 + 128]);
    float denom = 0.f, a0 = 0.f, a1 = 0.f;
    int d0 = lane << 1;
    for (int cc = 0; cc < nch; ++cc) {
        const float* pg = base + (size_t)cc * 528;
        float w = __expf(pg[128] - M);
        denom += w * pg[129];
        a0 += w * pg[d0];
        a1 += w * pg[d0 + 1];
    }
    float inv = 1.f / denom;
    float* dst = attn + (size_t)b * 4096 + (size_t)(h * 4 + g) * 128 + d0;
    dst[0] = a0 * inv;
    dst[1] = a1 * inv;
}

// ---------------------------------------------------------------------------
// Workspace (floats): qb[32][4096] @0, knb[32*1024] @131072, vnb @163840,
// attn[32][4096] @196608, part[32*8*16*4*132] @327680 (~8.7MB).
// NO memsets: all outputs fully written (no atomics anywhere).
// ---------------------------------------------------------------------------
extern "C" void kernel_launch(void* const* d_in, const int* in_sizes, int n_in,
                              void* d_out, int out_size, void* d_ws, size_t ws_size,
                              hipStream_t stream)
{
    const float* x   = (const float*)d_in[0];
    const float* wq  = (const float*)d_in[1];
    const float* wk  = (const float*)d_in[2];
    const float* wv  = (const float*)d_in[3];
    const float* wo  = (const float*)d_in[4];
    const float* kc  = (const float*)d_in[5];
    const float* vc  = (const float*)d_in[6];
    const int* btab  = (const int*)d_in[8];
    const int* lens  = (const int*)d_in[10];

    float* qb   = (float*)d_ws;
    float* knb  = qb  + 32 * 4096;
    float* vnb  = knb + 32 * 1024;
    float* attn = vnb + 32 * 1024;
    float* part = attn + 32 * 4096;
    float* outp = (float*)d_out;

    qkv_mfma<<<768, 256, 0, stream>>>(x, wq, wk, wv, qb, knb, vnb);
    rope_kernel<<<32 * 40, 64, 0, stream>>>(qb, knb, lens);
    attn_kernel<<<512, 512, 0, stream>>>(kc, vc, qb, knb, vnb, btab, lens, part);
    combine_kernel<<<256, 256, 0, stream>>>(part, lens, attn);
    wo_mfma<<<512, 256, 0, stream>>>(attn, wo, outp);
}

// Round 16
// 155.460 us; speedup vs baseline: 1.5996x; 1.0580x over previous
//
#include <hip/hip_runtime.h>
#include <hip/hip_bf16.h>
#include <math.h>

// B=32, HID=4096, NH=32, NKV=8, HS=128, BS=16, MAXS=2048, groups=4

typedef __attribute__((ext_vector_type(8))) short bf16x8;
typedef __attribute__((ext_vector_type(4))) float f32x4;

// ---------------------------------------------------------------------------
// bf16 MFMA GEMM v3: one block per 16n x 32m C-tile; 8 waves = K=512 splits;
// both m-halves share each w-fragment (25% fewer loads than R14); LDS reduce,
// coalesced stores, no atomics. cvt via __float2bfloat16 (compiler v_cvt_pk)
// instead of the ~40-instr bit-trick.
// ---------------------------------------------------------------------------
__device__ __forceinline__ short f2bfs(float f) {
    __hip_bfloat16 h = __float2bfloat16(f);
    unsigned short u;
    __builtin_memcpy(&u, &h, 2);
    return (short)u;
}
__device__ __forceinline__ bf16x8 cvt8(float4 a, float4 b) {
    bf16x8 r;
    r[0] = f2bfs(a.x); r[1] = f2bfs(a.y); r[2] = f2bfs(a.z); r[3] = f2bfs(a.w);
    r[4] = f2bfs(b.x); r[5] = f2bfs(b.y); r[6] = f2bfs(b.z); r[7] = f2bfs(b.w);
    return r;
}

__device__ __forceinline__ void mfma_block8(
    const float* __restrict__ xp0, const float* __restrict__ xp1,
    const float* __restrict__ wp, float* __restrict__ dst, int dstr, int n0)
{
    __shared__ float red[8][64][8];
    int wave = threadIdx.x >> 6, lane = threadIdx.x & 63;
    f32x4 acc0 = {0.f, 0.f, 0.f, 0.f};
    f32x4 acc1 = {0.f, 0.f, 0.f, 0.f};
#pragma unroll 4
    for (int s = 0; s < 16; ++s) {
        float4 wa  = *(const float4*)(wp  + s * 32);
        float4 wb  = *(const float4*)(wp  + s * 32 + 4);
        float4 x0a = *(const float4*)(xp0 + s * 32);
        float4 x0b = *(const float4*)(xp0 + s * 32 + 4);
        float4 x1a = *(const float4*)(xp1 + s * 32);
        float4 x1b = *(const float4*)(xp1 + s * 32 + 4);
        bf16x8 wf = cvt8(wa, wb);
        acc0 = __builtin_amdgcn_mfma_f32_16x16x32_bf16(cvt8(x0a, x0b), wf, acc0, 0, 0, 0);
        acc1 = __builtin_amdgcn_mfma_f32_16x16x32_bf16(cvt8(x1a, x1b), wf, acc1, 0, 0, 0);
    }
#pragma unroll
    for (int j = 0; j < 4; ++j) { red[wave][lane][j] = acc0[j]; red[wave][lane][4 + j] = acc1[j]; }
    __syncthreads();
    if (threadIdx.x < 128) {
        int l = threadIdx.x & 63, half = threadIdx.x >> 6;
        int ccol = n0 + (l & 15);
        int rbase = half * 16 + ((l >> 4) << 2);
#pragma unroll
        for (int j = 0; j < 4; ++j) {
            int e = (half << 2) + j;
            float s = red[0][l][e] + red[1][l][e] + red[2][l][e] + red[3][l][e]
                    + red[4][l][e] + red[5][l][e] + red[6][l][e] + red[7][l][e];
            dst[(size_t)(rbase + j) * dstr + ccol] = s;
        }
    }
}

// grid = 384 blocks x 512 thr (256 q-tiles, 64 k, 64 v)
__global__ __launch_bounds__(512) void qkv_mfma(
    const float* __restrict__ x, const float* __restrict__ wq,
    const float* __restrict__ wk, const float* __restrict__ wv,
    float* __restrict__ qb, float* __restrict__ knb, float* __restrict__ vnb)
{
    int nt = blockIdx.x;
    int wave = threadIdx.x >> 6, lane = threadIdx.x & 63;
    const float* w; float* dst; int dstr; int n0;
    if (nt < 256)      { w = wq; n0 = nt * 16;         dst = qb;  dstr = 4096; }
    else if (nt < 320) { w = wk; n0 = (nt - 256) * 16; dst = knb; dstr = 1024; }
    else               { w = wv; n0 = (nt - 320) * 16; dst = vnb; dstr = 1024; }
    int row = lane & 15, kq = (lane >> 4) << 3;
    int kbase = wave << 9;
    const float* xp0 = x + (size_t)row * 4096 + kbase + kq;
    const float* xp1 = xp0 + (size_t)16 * 4096;
    const float* wp  = w + (size_t)(n0 + row) * 4096 + kbase + kq;
    mfma_block8(xp0, xp1, wp, dst, dstr, n0);
}

// grid = 256 blocks x 512 thr
__global__ __launch_bounds__(512) void wo_mfma(
    const float* __restrict__ attn, const float* __restrict__ wo,
    float* __restrict__ out)
{
    int nt = blockIdx.x;
    int wave = threadIdx.x >> 6, lane = threadIdx.x & 63;
    int n0 = nt * 16;
    int row = lane & 15, kq = (lane >> 4) << 3;
    int kbase = wave << 9;
    const float* xp0 = attn + (size_t)row * 4096 + kbase + kq;
    const float* xp1 = xp0 + (size_t)16 * 4096;
    const float* wp  = wo + (size_t)(n0 + row) * 4096 + kbase + kq;
    mfma_block8(xp0, xp1, wp, out, 4096, n0);
}

// ---------------------------------------------------------------------------
// Flash-decode attention v7 = v6 + fused RoPE (rope_kernel dispatch removed).
// Block = (b, 128-chunk), 8 waves = 8 kv-heads (v6 co-scheduling, proven).
// Prologue: per-block cos/sin table (64 sincosf into LDS), q roped IN-REG
// (d/d+64 pair is exactly 8 lanes apart -> shfl_xor(...,8)), then prescaled.
// New-token position handled as an explicit TAIL step (load knb/vnb, rope k
// in-reg, one extra online-softmax update, subgroup g==0 only) -> the main
// loop is pure cache streaming with NO per-position select. 2-deep prefetch
// (depth 3 was null R9-vs-R10; saves 16 VGPR toward 4 waves/SIMD).
// All staging regs named scalars (rule #20). launch_bounds(512,1): never cap.
// ---------------------------------------------------------------------------
#define MUL4(V, S) { V.x *= S; V.y *= S; V.z *= S; V.w *= S; }
#define FMA4(O, P, V) { O.x = fmaf(P, V.x, O.x); O.y = fmaf(P, V.y, O.y); \
                        O.z = fmaf(P, V.z, O.z); O.w = fmaf(P, V.w, O.w); }
#define DOT8(S, QA, QB, K0, K1) { \
    S = fmaf(QA.x, K0.x, S); S = fmaf(QA.y, K0.y, S); \
    S = fmaf(QA.z, K0.z, S); S = fmaf(QA.w, K0.w, S); \
    S = fmaf(QB.x, K1.x, S); S = fmaf(QB.y, K1.y, S); \
    S = fmaf(QB.z, K1.z, S); S = fmaf(QB.w, K1.w, S); }
#define RED16(X) { X += __shfl_xor(X, 1, 64); X += __shfl_xor(X, 2, 64); \
                   X += __shfl_xor(X, 4, 64); X += __shfl_xor(X, 8, 64); }
#define REDG_SUM(X) { X += __shfl_xor(X, 16, 64); X += __shfl_xor(X, 32, 64); }
#define REDG_MAX(X) { X = fmaxf(X, __shfl_xor(X, 16, 64)); \
                      X = fmaxf(X, __shfl_xor(X, 32, 64)); }
#define REDG_SUM4(V) { REDG_SUM(V.x) REDG_SUM(V.y) REDG_SUM(V.z) REDG_SUM(V.w) }

// in-register rope of an 8-float slice (A=j0..3, B=j4..7) using cs[] + shfl
#define ROPE8(A, B) { \
    float pax = __shfl_xor(A.x, 8, 64), pay = __shfl_xor(A.y, 8, 64); \
    float paz = __shfl_xor(A.z, 8, 64), paw = __shfl_xor(A.w, 8, 64); \
    float pbx = __shfl_xor(B.x, 8, 64), pby = __shfl_xor(B.y, 8, 64); \
    float pbz = __shfl_xor(B.z, 8, 64), pbw = __shfl_xor(B.w, 8, 64); \
    int ci = (i & 7) << 3; \
    float2 c0 = cs[ci + 0], c1 = cs[ci + 1], c2 = cs[ci + 2], c3 = cs[ci + 3]; \
    float2 c4 = cs[ci + 4], c5 = cs[ci + 5], c6 = cs[ci + 6], c7 = cs[ci + 7]; \
    float sg = (i < 8) ? -1.f : 1.f; \
    A.x = fmaf(sg * pax, c0.y, A.x * c0.x); \
    A.y = fmaf(sg * pay, c1.y, A.y * c1.x); \
    A.z = fmaf(sg * paz, c2.y, A.z * c2.x); \
    A.w = fmaf(sg * paw, c3.y, A.w * c3.x); \
    B.x = fmaf(sg * pbx, c4.y, B.x * c4.x); \
    B.y = fmaf(sg * pby, c5.y, B.y * c5.x); \
    B.z = fmaf(sg * pbz, c6.y, B.z * c6.x); \
    B.w = fmaf(sg * pbw, c7.y, B.w * c7.x); }

#define ALOADR(S, r_) { \
    int sl = ss[((r_) << 2) + g]; \
    const float* kp = kc + (size_t)sl * 1024 + hoff + isl; \
    const float* vp = vc + (size_t)sl * 1024 + hoff + isl; \
    S##k0 = *(const float4*)(kp); S##k1 = *(const float4*)(kp + 4); \
    S##v0 = *(const float4*)(vp); S##v1 = *(const float4*)(vp + 4); }

#define OUPD(s_, m_, l_, Oa_, Ob_, V0_, V1_, vld_) { \
    if (s_ > m_) { \
        float c_ = __expf(m_ - s_); \
        l_ *= c_; MUL4(Oa_, c_) MUL4(Ob_, c_) \
        m_ = s_; \
    } \
    float pe_ = vld_ ? __expf(s_ - m_) : 0.f; \
    l_ += pe_; \
    FMA4(Oa_, pe_, V0_) FMA4(Ob_, pe_, V1_) }

#define ACOMP(S, r_) { \
    float s0 = 0.f, s1 = 0.f, s2 = 0.f, s3 = 0.f; \
    DOT8(s0, q0a, q0b, S##k0, S##k1) \
    DOT8(s1, q1a, q1b, S##k0, S##k1) \
    DOT8(s2, q2a, q2b, S##k0, S##k1) \
    DOT8(s3, q3a, q3b, S##k0, S##k1) \
    RED16(s0) RED16(s1) RED16(s2) RED16(s3) \
    int vld = (((r_) << 2) + g) < cend; \
    if (!vld) { s0 = s1 = s2 = s3 = -INFINITY; } \
    OUPD(s0, m0, l0, o0a, o0b, S##v0, S##v1, vld) \
    OUPD(s1, m1, l1, o1a, o1b, S##v0, S##v1, vld) \
    OUPD(s2, m2, l2, o2a, o2b, S##v0, S##v1, vld) \
    OUPD(s3, m3, l3, o3a, o3b, S##v0, S##v1, vld) }

__global__ __launch_bounds__(512, 1) void attn_kernel(
    const float* __restrict__ kc, const float* __restrict__ vc,
    const float* __restrict__ qb, const float* __restrict__ knb,
    const float* __restrict__ vnb,
    const int* __restrict__ btab, const int* __restrict__ lens,
    float* __restrict__ part)
{
    int bid = blockIdx.x;
    int c = bid >> 5, b = bid & 31;     // chunk-major for CU balance
    int len = lens[b];
    int p0 = c << 7;
    if (p0 >= len) return;
    int last = len - 1;                 // new-token position (>= p0 always here)
    int cend = min(last - p0, 128);     // cached positions in this chunk
    int hasTail = (last - p0) < 128;
    int nr = (cend + 3) >> 2;

    __shared__ int ss[128];
    __shared__ float2 cs[64];           // rope cos/sin for pos = last

    int t = threadIdx.x;
    int h = t >> 6;                     // wave = kv-head
    int lane = t & 63;
    int g = lane >> 4;                  // position-in-round 0..3
    int i = lane & 15;
    int isl = i << 3;                   // dim slice base
    int hoff = h * 128;

    if (t < 64) {                       // rope table: d' = t
        float inv = exp2f(-(float)t * 0.20762050593046014f);
        float fr = (float)last * inv;
        float s_, c_;
        sincosf(fr, &s_, &c_);
        cs[t] = make_float2(c_, s_);
    } else if (t < 128) {               // slot table (all entries valid slots)
        int idx = (t - 64) << 1;
        int p = p0 + idx;
        int bt = btab[b * 128 + (p >> 4)];
        ss[idx]     = bt * 16 + (p & 15);
        ss[idx + 1] = bt * 16 + (p & 15) + 1;
    }
    __syncthreads();

    // q for this kv-head's 4 GQA heads: load, ROPE in-reg, prescale
    const float scale = 0.08838834764831845f;   // 1/sqrt(128)
    const float* qrow = qb + (size_t)b * 4096 + (size_t)h * 512;
    float4 q0a = *(const float4*)(qrow + isl),       q0b = *(const float4*)(qrow + isl + 4);
    float4 q1a = *(const float4*)(qrow + 128 + isl), q1b = *(const float4*)(qrow + 128 + isl + 4);
    float4 q2a = *(const float4*)(qrow + 256 + isl), q2b = *(const float4*)(qrow + 256 + isl + 4);
    float4 q3a = *(const float4*)(qrow + 384 + isl), q3b = *(const float4*)(qrow + 384 + isl + 4);
    ROPE8(q0a, q0b) ROPE8(q1a, q1b) ROPE8(q2a, q2b) ROPE8(q3a, q3b)
    MUL4(q0a, scale) MUL4(q0b, scale) MUL4(q1a, scale) MUL4(q1b, scale)
    MUL4(q2a, scale) MUL4(q2b, scale) MUL4(q3a, scale) MUL4(q3b, scale)

    float m0 = -INFINITY, m1 = -INFINITY, m2 = -INFINITY, m3 = -INFINITY;
    float l0 = 0.f, l1 = 0.f, l2 = 0.f, l3 = 0.f;
    float4 o0a = {0,0,0,0}, o0b = {0,0,0,0}, o1a = {0,0,0,0}, o1b = {0,0,0,0};
    float4 o2a = {0,0,0,0}, o2b = {0,0,0,0}, o3a = {0,0,0,0}, o3b = {0,0,0,0};

    // ---- tail: the new-token position (rope k_new in-reg; v not roped) ----
    if (hasTail) {
        const float* kn = knb + ((size_t)b * 8 + h) * 128 + isl;
        const float* vn = vnb + ((size_t)b * 8 + h) * 128 + isl;
        float4 tk0 = *(const float4*)(kn), tk1 = *(const float4*)(kn + 4);
        float4 tv0 = *(const float4*)(vn), tv1 = *(const float4*)(vn + 4);
        ROPE8(tk0, tk1)
        float s0 = 0.f, s1 = 0.f, s2 = 0.f, s3 = 0.f;
        DOT8(s0, q0a, q0b, tk0, tk1)
        DOT8(s1, q1a, q1b, tk0, tk1)
        DOT8(s2, q2a, q2b, tk0, tk1)
        DOT8(s3, q3a, q3b, tk0, tk1)
        RED16(s0) RED16(s1) RED16(s2) RED16(s3)
        int vld = (g == 0);
        if (!vld) { s0 = s1 = s2 = s3 = -INFINITY; }
        OUPD(s0, m0, l0, o0a, o0b, tv0, tv1, vld)
        OUPD(s1, m1, l1, o1a, o1b, tv0, tv1, vld)
        OUPD(s2, m2, l2, o2a, o2b, tv0, tv1, vld)
        OUPD(s3, m3, l3, o3a, o3b, tv0, tv1, vld)
    }

    // ---- main loop: pure cache streaming, 2-deep named-reg prefetch ----
    float4 ak0, ak1, av0, av1;
    float4 bk0, bk1, bv0, bv1;
    if (nr > 0) {
        ALOADR(a, 0)
        if (1 < nr) ALOADR(b, 1)
        for (int r = 0; r < nr; r += 2) {
            ACOMP(a, r)
            if (r + 2 < nr) ALOADR(a, r + 2)
            if (r + 1 >= nr) break;
            ACOMP(b, r + 1)
            if (r + 3 < nr) ALOADR(b, r + 3)
        }
    }

    // merge the 4 subgroup partial softmaxes (once per wave)
    float M0 = m0, M1 = m1, M2 = m2, M3 = m3;
    REDG_MAX(M0) REDG_MAX(M1) REDG_MAX(M2) REDG_MAX(M3)
    float w0 = __expf(m0 - M0), w1 = __expf(m1 - M1);
    float w2 = __expf(m2 - M2), w3 = __expf(m3 - M3);
    float L0 = w0 * l0, L1 = w1 * l1, L2 = w2 * l2, L3 = w3 * l3;
    REDG_SUM(L0) REDG_SUM(L1) REDG_SUM(L2) REDG_SUM(L3)
    MUL4(o0a, w0) MUL4(o0b, w0) MUL4(o1a, w1) MUL4(o1b, w1)
    MUL4(o2a, w2) MUL4(o2b, w2) MUL4(o3a, w3) MUL4(o3b, w3)
    REDG_SUM4(o0a) REDG_SUM4(o0b) REDG_SUM4(o1a) REDG_SUM4(o1b)
    REDG_SUM4(o2a) REDG_SUM4(o2b) REDG_SUM4(o3a) REDG_SUM4(o3b)

    // partial layout: per (b,h,c): 4 heads x 132 floats [O[128], m, l, pad2]
    float* pgb = part + (size_t)(((b * 8 + h) * 16 + c) * 4) * 132;
    if (lane < 16) {
        *(float4*)(pgb +       isl) = o0a; *(float4*)(pgb +       isl + 4) = o0b;
        *(float4*)(pgb + 132 + isl) = o1a; *(float4*)(pgb + 132 + isl + 4) = o1b;
        *(float4*)(pgb + 264 + isl) = o2a; *(float4*)(pgb + 264 + isl + 4) = o2b;
        *(float4*)(pgb + 396 + isl) = o3a; *(float4*)(pgb + 396 + isl + 4) = o3b;
    }
    if (lane == 0) {
        pgb[128] = M0; pgb[129] = L0;
        pgb[260] = M1; pgb[261] = L1;
        pgb[392] = M2; pgb[393] = L2;
        pgb[524] = M3; pgb[525] = L3;
    }
}

// grid = 256 (b*8+h), block = 256 (4 heads x 64 lanes)
__global__ __launch_bounds__(256) void combine_kernel(
    const float* __restrict__ part, const int* __restrict__ lens,
    float* __restrict__ attn)
{
    int b = blockIdx.x >> 3, h = blockIdx.x & 7;
    int t = threadIdx.x;
    int g = t >> 6, lane = t & 63;
    int len = lens[b];
    int nch = (len + 127) >> 7;
    const float* base = part + (size_t)(b * 8 + h) * 8448 + (size_t)g * 132;
    float M = -INFINITY;
    for (int cc = 0; cc < nch; ++cc)
        M = fmaxf(M, base[(size_t)cc * 528 + 128]);
    float denom = 0.f, a0 = 0.f, a1 = 0.f;
    int d0 = lane << 1;
    for (int cc = 0; cc < nch; ++cc) {
        const float* pg = base + (size_t)cc * 528;
        float w = __expf(pg[128] - M);
        denom += w * pg[129];
        a0 += w * pg[d0];
        a1 += w * pg[d0 + 1];
    }
    float inv = 1.f / denom;
    float* dst = attn + (size_t)b * 4096 + (size_t)(h * 4 + g) * 128 + d0;
    dst[0] = a0 * inv;
    dst[1] = a1 * inv;
}

// ---------------------------------------------------------------------------
// Workspace (floats): qb[32][4096] @0, knb[32*1024] @131072, vnb @163840,
// attn[32][4096] @196608, part[32*8*16*4*132] @327680 (~8.7MB).
// NO memsets: all outputs fully written (no atomics anywhere). 4 dispatches.
// ---------------------------------------------------------------------------
extern "C" void kernel_launch(void* const* d_in, const int* in_sizes, int n_in,
                              void* d_out, int out_size, void* d_ws, size_t ws_size,
                              hipStream_t stream)
{
    const float* x   = (const float*)d_in[0];
    const float* wq  = (const float*)d_in[1];
    const float* wk  = (const float*)d_in[2];
    const float* wv  = (const float*)d_in[3];
    const float* wo  = (const float*)d_in[4];
    const float* kc  = (const float*)d_in[5];
    const float* vc  = (const float*)d_in[6];
    const int* btab  = (const int*)d_in[8];
    const int* lens  = (const int*)d_in[10];

    float* qb   = (float*)d_ws;
    float* knb  = qb  + 32 * 4096;
    float* vnb  = knb + 32 * 1024;
    float* attn = vnb + 32 * 1024;
    float* part = attn + 32 * 4096;
    float* outp = (float*)d_out;

    qkv_mfma<<<384, 512, 0, stream>>>(x, wq, wk, wv, qb, knb, vnb);
    attn_kernel<<<512, 512, 0, stream>>>(kc, vc, qb, knb, vnb, btab, lens, part);
    combine_kernel<<<256, 256, 0, stream>>>(part, lens, attn);
    wo_mfma<<<256, 512, 0, stream>>>(attn, wo, outp);
}

// Round 17
// 154.129 us; speedup vs baseline: 1.6134x; 1.0086x over previous
//
#include <hip/hip_runtime.h>
#include <hip/hip_bf16.h>
#include <math.h>

// B=32, HID=4096, NH=32, NKV=8, HS=128, BS=16, MAXS=2048, groups=4

typedef __attribute__((ext_vector_type(8))) short bf16x8;
typedef __attribute__((ext_vector_type(4))) float f32x4;

// ---------------------------------------------------------------------------
// bf16 MFMA GEMM v3 (R16, proven): one block per 16n x 32m C-tile; 8 waves =
// K=512 splits; w-fragment shared by both m-halves; LDS reduce; no atomics.
// ---------------------------------------------------------------------------
__device__ __forceinline__ short f2bfs(float f) {
    __hip_bfloat16 h = __float2bfloat16(f);
    unsigned short u;
    __builtin_memcpy(&u, &h, 2);
    return (short)u;
}
__device__ __forceinline__ bf16x8 cvt8(float4 a, float4 b) {
    bf16x8 r;
    r[0] = f2bfs(a.x); r[1] = f2bfs(a.y); r[2] = f2bfs(a.z); r[3] = f2bfs(a.w);
    r[4] = f2bfs(b.x); r[5] = f2bfs(b.y); r[6] = f2bfs(b.z); r[7] = f2bfs(b.w);
    return r;
}

__device__ __forceinline__ void mfma_block8(
    const float* __restrict__ xp0, const float* __restrict__ xp1,
    const float* __restrict__ wp, float* __restrict__ dst, int dstr, int n0)
{
    __shared__ float red[8][64][8];
    int wave = threadIdx.x >> 6, lane = threadIdx.x & 63;
    f32x4 acc0 = {0.f, 0.f, 0.f, 0.f};
    f32x4 acc1 = {0.f, 0.f, 0.f, 0.f};
#pragma unroll 4
    for (int s = 0; s < 16; ++s) {
        float4 wa  = *(const float4*)(wp  + s * 32);
        float4 wb  = *(const float4*)(wp  + s * 32 + 4);
        float4 x0a = *(const float4*)(xp0 + s * 32);
        float4 x0b = *(const float4*)(xp0 + s * 32 + 4);
        float4 x1a = *(const float4*)(xp1 + s * 32);
        float4 x1b = *(const float4*)(xp1 + s * 32 + 4);
        bf16x8 wf = cvt8(wa, wb);
        acc0 = __builtin_amdgcn_mfma_f32_16x16x32_bf16(cvt8(x0a, x0b), wf, acc0, 0, 0, 0);
        acc1 = __builtin_amdgcn_mfma_f32_16x16x32_bf16(cvt8(x1a, x1b), wf, acc1, 0, 0, 0);
    }
#pragma unroll
    for (int j = 0; j < 4; ++j) { red[wave][lane][j] = acc0[j]; red[wave][lane][4 + j] = acc1[j]; }
    __syncthreads();
    if (threadIdx.x < 128) {
        int l = threadIdx.x & 63, half = threadIdx.x >> 6;
        int ccol = n0 + (l & 15);
        int rbase = half * 16 + ((l >> 4) << 2);
#pragma unroll
        for (int j = 0; j < 4; ++j) {
            int e = (half << 2) + j;
            float s = red[0][l][e] + red[1][l][e] + red[2][l][e] + red[3][l][e]
                    + red[4][l][e] + red[5][l][e] + red[6][l][e] + red[7][l][e];
            dst[(size_t)(rbase + j) * dstr + ccol] = s;
        }
    }
}

// grid = 384 blocks x 512 thr (256 q-tiles, 64 k, 64 v)
__global__ __launch_bounds__(512) void qkv_mfma(
    const float* __restrict__ x, const float* __restrict__ wq,
    const float* __restrict__ wk, const float* __restrict__ wv,
    float* __restrict__ qb, float* __restrict__ knb, float* __restrict__ vnb)
{
    int nt = blockIdx.x;
    int wave = threadIdx.x >> 6, lane = threadIdx.x & 63;
    const float* w; float* dst; int dstr; int n0;
    if (nt < 256)      { w = wq; n0 = nt * 16;         dst = qb;  dstr = 4096; }
    else if (nt < 320) { w = wk; n0 = (nt - 256) * 16; dst = knb; dstr = 1024; }
    else               { w = wv; n0 = (nt - 320) * 16; dst = vnb; dstr = 1024; }
    int row = lane & 15, kq = (lane >> 4) << 3;
    int kbase = wave << 9;
    const float* xp0 = x + (size_t)row * 4096 + kbase + kq;
    const float* xp1 = xp0 + (size_t)16 * 4096;
    const float* wp  = w + (size_t)(n0 + row) * 4096 + kbase + kq;
    mfma_block8(xp0, xp1, wp, dst, dstr, n0);
}

// grid = 256 blocks x 512 thr
__global__ __launch_bounds__(512) void wo_mfma(
    const float* __restrict__ attn, const float* __restrict__ wo,
    float* __restrict__ out)
{
    int nt = blockIdx.x;
    int wave = threadIdx.x >> 6, lane = threadIdx.x & 63;
    int n0 = nt * 16;
    int row = lane & 15, kq = (lane >> 4) << 3;
    int kbase = wave << 9;
    const float* xp0 = attn + (size_t)row * 4096 + kbase + kq;
    const float* xp1 = xp0 + (size_t)16 * 4096;
    const float* wp  = wo + (size_t)(n0 + row) * 4096 + kbase + kq;
    mfma_block8(xp0, xp1, wp, out, 4096, n0);
}

// ---------------------------------------------------------------------------
// Flash-decode attention v8 = v7 math, 128-thread blocks (2 kv-heads each).
// MAKESPAN FIX: v7's 512-thr blocks at ~150 VGPR fit ONE per CU; ~270 active
// blocks on 256 CUs -> 14 CUs run a 2nd serial round while 242 idle (~2x
// makespan; why all per-wave tuning was null). v8: 4x more, 4x smaller
// blocks (grid 2048, ~1080 active, 6-block/CU capacity vs 4.2 avg) -> all
// co-resident, HW scheduler balances dynamically. Sibling hp blocks adjacent
// in dispatch (hp = low bits) to keep v6's temporal head co-scheduling.
// Per-wave code identical to v7: fused rope (q in-reg via shfl_xor(..,8),
// per-block cos/sin LDS table), explicit new-token tail, pure cache-stream
// main loop, 2-deep named-scalar prefetch (rule #20).
// ---------------------------------------------------------------------------
#define MUL4(V, S) { V.x *= S; V.y *= S; V.z *= S; V.w *= S; }
#define FMA4(O, P, V) { O.x = fmaf(P, V.x, O.x); O.y = fmaf(P, V.y, O.y); \
                        O.z = fmaf(P, V.z, O.z); O.w = fmaf(P, V.w, O.w); }
#define DOT8(S, QA, QB, K0, K1) { \
    S = fmaf(QA.x, K0.x, S); S = fmaf(QA.y, K0.y, S); \
    S = fmaf(QA.z, K0.z, S); S = fmaf(QA.w, K0.w, S); \
    S = fmaf(QB.x, K1.x, S); S = fmaf(QB.y, K1.y, S); \
    S = fmaf(QB.z, K1.z, S); S = fmaf(QB.w, K1.w, S); }
#define RED16(X) { X += __shfl_xor(X, 1, 64); X += __shfl_xor(X, 2, 64); \
                   X += __shfl_xor(X, 4, 64); X += __shfl_xor(X, 8, 64); }
#define REDG_SUM(X) { X += __shfl_xor(X, 16, 64); X += __shfl_xor(X, 32, 64); }
#define REDG_MAX(X) { X = fmaxf(X, __shfl_xor(X, 16, 64)); \
                      X = fmaxf(X, __shfl_xor(X, 32, 64)); }
#define REDG_SUM4(V) { REDG_SUM(V.x) REDG_SUM(V.y) REDG_SUM(V.z) REDG_SUM(V.w) }

// in-register rope of an 8-float slice (A=j0..3, B=j4..7) using cs[] + shfl
#define ROPE8(A, B) { \
    float pax = __shfl_xor(A.x, 8, 64), pay = __shfl_xor(A.y, 8, 64); \
    float paz = __shfl_xor(A.z, 8, 64), paw = __shfl_xor(A.w, 8, 64); \
    float pbx = __shfl_xor(B.x, 8, 64), pby = __shfl_xor(B.y, 8, 64); \
    float pbz = __shfl_xor(B.z, 8, 64), pbw = __shfl_xor(B.w, 8, 64); \
    int ci = (i & 7) << 3; \
    float2 c0 = cs[ci + 0], c1 = cs[ci + 1], c2 = cs[ci + 2], c3 = cs[ci + 3]; \
    float2 c4 = cs[ci + 4], c5 = cs[ci + 5], c6 = cs[ci + 6], c7 = cs[ci + 7]; \
    float sg = (i < 8) ? -1.f : 1.f; \
    A.x = fmaf(sg * pax, c0.y, A.x * c0.x); \
    A.y = fmaf(sg * pay, c1.y, A.y * c1.x); \
    A.z = fmaf(sg * paz, c2.y, A.z * c2.x); \
    A.w = fmaf(sg * paw, c3.y, A.w * c3.x); \
    B.x = fmaf(sg * pbx, c4.y, B.x * c4.x); \
    B.y = fmaf(sg * pby, c5.y, B.y * c5.x); \
    B.z = fmaf(sg * pbz, c6.y, B.z * c6.x); \
    B.w = fmaf(sg * pbw, c7.y, B.w * c7.x); }

#define ALOADR(S, r_) { \
    int sl = ss[((r_) << 2) + g]; \
    const float* kp = kc + (size_t)sl * 1024 + hoff + isl; \
    const float* vp = vc + (size_t)sl * 1024 + hoff + isl; \
    S##k0 = *(const float4*)(kp); S##k1 = *(const float4*)(kp + 4); \
    S##v0 = *(const float4*)(vp); S##v1 = *(const float4*)(vp + 4); }

#define OUPD(s_, m_, l_, Oa_, Ob_, V0_, V1_, vld_) { \
    if (s_ > m_) { \
        float c_ = __expf(m_ - s_); \
        l_ *= c_; MUL4(Oa_, c_) MUL4(Ob_, c_) \
        m_ = s_; \
    } \
    float pe_ = vld_ ? __expf(s_ - m_) : 0.f; \
    l_ += pe_; \
    FMA4(Oa_, pe_, V0_) FMA4(Ob_, pe_, V1_) }

#define ACOMP(S, r_) { \
    float s0 = 0.f, s1 = 0.f, s2 = 0.f, s3 = 0.f; \
    DOT8(s0, q0a, q0b, S##k0, S##k1) \
    DOT8(s1, q1a, q1b, S##k0, S##k1) \
    DOT8(s2, q2a, q2b, S##k0, S##k1) \
    DOT8(s3, q3a, q3b, S##k0, S##k1) \
    RED16(s0) RED16(s1) RED16(s2) RED16(s3) \
    int vld = (((r_) << 2) + g) < cend; \
    if (!vld) { s0 = s1 = s2 = s3 = -INFINITY; } \
    OUPD(s0, m0, l0, o0a, o0b, S##v0, S##v1, vld) \
    OUPD(s1, m1, l1, o1a, o1b, S##v0, S##v1, vld) \
    OUPD(s2, m2, l2, o2a, o2b, S##v0, S##v1, vld) \
    OUPD(s3, m3, l3, o3a, o3b, S##v0, S##v1, vld) }

__global__ __launch_bounds__(128, 1) void attn_kernel(
    const float* __restrict__ kc, const float* __restrict__ vc,
    const float* __restrict__ qb, const float* __restrict__ knb,
    const float* __restrict__ vnb,
    const int* __restrict__ btab, const int* __restrict__ lens,
    float* __restrict__ part)
{
    int bid = blockIdx.x;
    int hp = bid & 3;                   // head-pair within (b,c)
    int idx = bid >> 2;
    int c = idx >> 5, b = idx & 31;     // chunk-major for CU balance
    int len = lens[b];
    int p0 = c << 7;
    if (p0 >= len) return;
    int last = len - 1;                 // new-token position
    int cend = min(last - p0, 128);     // cached positions in this chunk
    int hasTail = (last - p0) < 128;
    int nr = (cend + 3) >> 2;

    __shared__ int ss[128];
    __shared__ float2 cs[64];           // rope cos/sin for pos = last

    int t = threadIdx.x;                // 0..127
    int h = (hp << 1) | (t >> 6);       // global kv-head 0..7
    int lane = t & 63;
    int g = lane >> 4;                  // position-in-round 0..3
    int i = lane & 15;
    int isl = i << 3;                   // dim slice base
    int hoff = h * 128;

    if (t < 64) {                       // rope table: d' = t
        float inv = exp2f(-(float)t * 0.20762050593046014f);
        float fr = (float)last * inv;
        float s_, c_;
        sincosf(fr, &s_, &c_);
        cs[t] = make_float2(c_, s_);
    } else {                            // slot table (all entries valid slots)
        int idx2 = (t - 64) << 1;
        int p = p0 + idx2;
        int bt = btab[b * 128 + (p >> 4)];
        ss[idx2]     = bt * 16 + (p & 15);
        ss[idx2 + 1] = bt * 16 + (p & 15) + 1;
    }
    __syncthreads();

    // q for this kv-head's 4 GQA heads: load, ROPE in-reg, prescale
    const float scale = 0.08838834764831845f;   // 1/sqrt(128)
    const float* qrow = qb + (size_t)b * 4096 + (size_t)h * 512;
    float4 q0a = *(const float4*)(qrow + isl),       q0b = *(const float4*)(qrow + isl + 4);
    float4 q1a = *(const float4*)(qrow + 128 + isl), q1b = *(const float4*)(qrow + 128 + isl + 4);
    float4 q2a = *(const float4*)(qrow + 256 + isl), q2b = *(const float4*)(qrow + 256 + isl + 4);
    float4 q3a = *(const float4*)(qrow + 384 + isl), q3b = *(const float4*)(qrow + 384 + isl + 4);
    ROPE8(q0a, q0b) ROPE8(q1a, q1b) ROPE8(q2a, q2b) ROPE8(q3a, q3b)
    MUL4(q0a, scale) MUL4(q0b, scale) MUL4(q1a, scale) MUL4(q1b, scale)
    MUL4(q2a, scale) MUL4(q2b, scale) MUL4(q3a, scale) MUL4(q3b, scale)

    float m0 = -INFINITY, m1 = -INFINITY, m2 = -INFINITY, m3 = -INFINITY;
    float l0 = 0.f, l1 = 0.f, l2 = 0.f, l3 = 0.f;
    float4 o0a = {0,0,0,0}, o0b = {0,0,0,0}, o1a = {0,0,0,0}, o1b = {0,0,0,0};
    float4 o2a = {0,0,0,0}, o2b = {0,0,0,0}, o3a = {0,0,0,0}, o3b = {0,0,0,0};

    // ---- tail: the new-token position (rope k_new in-reg; v not roped) ----
    if (hasTail) {
        const float* kn = knb + ((size_t)b * 8 + h) * 128 + isl;
        const float* vn = vnb + ((size_t)b * 8 + h) * 128 + isl;
        float4 tk0 = *(const float4*)(kn), tk1 = *(const float4*)(kn + 4);
        float4 tv0 = *(const float4*)(vn), tv1 = *(const float4*)(vn + 4);
        ROPE8(tk0, tk1)
        float s0 = 0.f, s1 = 0.f, s2 = 0.f, s3 = 0.f;
        DOT8(s0, q0a, q0b, tk0, tk1)
        DOT8(s1, q1a, q1b, tk0, tk1)
        DOT8(s2, q2a, q2b, tk0, tk1)
        DOT8(s3, q3a, q3b, tk0, tk1)
        RED16(s0) RED16(s1) RED16(s2) RED16(s3)
        int vld = (g == 0);
        if (!vld) { s0 = s1 = s2 = s3 = -INFINITY; }
        OUPD(s0, m0, l0, o0a, o0b, tv0, tv1, vld)
        OUPD(s1, m1, l1, o1a, o1b, tv0, tv1, vld)
        OUPD(s2, m2, l2, o2a, o2b, tv0, tv1, vld)
        OUPD(s3, m3, l3, o3a, o3b, tv0, tv1, vld)
    }

    // ---- main loop: pure cache streaming, 2-deep named-reg prefetch ----
    float4 ak0, ak1, av0, av1;
    float4 bk0, bk1, bv0, bv1;
    if (nr > 0) {
        ALOADR(a, 0)
        if (1 < nr) ALOADR(b, 1)
        for (int r = 0; r < nr; r += 2) {
            ACOMP(a, r)
            if (r + 2 < nr) ALOADR(a, r + 2)
            if (r + 1 >= nr) break;
            ACOMP(b, r + 1)
            if (r + 3 < nr) ALOADR(b, r + 3)
        }
    }

    // merge the 4 subgroup partial softmaxes (once per wave)
    float M0 = m0, M1 = m1, M2 = m2, M3 = m3;
    REDG_MAX(M0) REDG_MAX(M1) REDG_MAX(M2) REDG_MAX(M3)
    float w0 = __expf(m0 - M0), w1 = __expf(m1 - M1);
    float w2 = __expf(m2 - M2), w3 = __expf(m3 - M3);
    float L0 = w0 * l0, L1 = w1 * l1, L2 = w2 * l2, L3 = w3 * l3;
    REDG_SUM(L0) REDG_SUM(L1) REDG_SUM(L2) REDG_SUM(L3)
    MUL4(o0a, w0) MUL4(o0b, w0) MUL4(o1a, w1) MUL4(o1b, w1)
    MUL4(o2a, w2) MUL4(o2b, w2) MUL4(o3a, w3) MUL4(o3b, w3)
    REDG_SUM4(o0a) REDG_SUM4(o0b) REDG_SUM4(o1a) REDG_SUM4(o1b)
    REDG_SUM4(o2a) REDG_SUM4(o2b) REDG_SUM4(o3a) REDG_SUM4(o3b)

    // partial layout: per (b,h,c): 4 heads x 132 floats [O[128], m, l, pad2]
    float* pgb = part + (size_t)(((b * 8 + h) * 16 + c) * 4) * 132;
    if (lane < 16) {
        *(float4*)(pgb +       isl) = o0a; *(float4*)(pgb +       isl + 4) = o0b;
        *(float4*)(pgb + 132 + isl) = o1a; *(float4*)(pgb + 132 + isl + 4) = o1b;
        *(float4*)(pgb + 264 + isl) = o2a; *(float4*)(pgb + 264 + isl + 4) = o2b;
        *(float4*)(pgb + 396 + isl) = o3a; *(float4*)(pgb + 396 + isl + 4) = o3b;
    }
    if (lane == 0) {
        pgb[128] = M0; pgb[129] = L0;
        pgb[260] = M1; pgb[261] = L1;
        pgb[392] = M2; pgb[393] = L2;
        pgb[524] = M3; pgb[525] = L3;
    }
}

// grid = 256 (b*8+h), block = 256 (4 heads x 64 lanes)
__global__ __launch_bounds__(256) void combine_kernel(
    const float* __restrict__ part, const int* __restrict__ lens,
    float* __restrict__ attn)
{
    int b = blockIdx.x >> 3, h = blockIdx.x & 7;
    int t = threadIdx.x;
    int g = t >> 6, lane = t & 63;
    int len = lens[b];
    int nch = (len + 127) >> 7;
    const float* base = part + (size_t)(b * 8 + h) * 8448 + (size_t)g * 132;
    float M = -INFINITY;
    for (int cc = 0; cc < nch; ++cc)
        M = fmaxf(M, base[(size_t)cc * 528 + 128]);
    float denom = 0.f, a0 = 0.f, a1 = 0.f;
    int d0 = lane << 1;
    for (int cc = 0; cc < nch; ++cc) {
        const float* pg = base + (size_t)cc * 528;
        float w = __expf(pg[128] - M);
        denom += w * pg[129];
        a0 += w * pg[d0];
        a1 += w * pg[d0 + 1];
    }
    float inv = 1.f / denom;
    float* dst = attn + (size_t)b * 4096 + (size_t)(h * 4 + g) * 128 + d0;
    dst[0] = a0 * inv;
    dst[1] = a1 * inv;
}

// ---------------------------------------------------------------------------
// Workspace (floats): qb[32][4096] @0, knb[32*1024] @131072, vnb @163840,
// attn[32][4096] @196608, part[32*8*16*4*132] @327680 (~8.7MB).
// NO memsets: all outputs fully written (no atomics anywhere). 4 dispatches.
// ---------------------------------------------------------------------------
extern "C" void kernel_launch(void* const* d_in, const int* in_sizes, int n_in,
                              void* d_out, int out_size, void* d_ws, size_t ws_size,
                              hipStream_t stream)
{
    const float* x   = (const float*)d_in[0];
    const float* wq  = (const float*)d_in[1];
    const float* wk  = (const float*)d_in[2];
    const float* wv  = (const float*)d_in[3];
    const float* wo  = (const float*)d_in[4];
    const float* kc  = (const float*)d_in[5];
    const float* vc  = (const float*)d_in[6];
    const int* btab  = (const int*)d_in[8];
    const int* lens  = (const int*)d_in[10];

    float* qb   = (float*)d_ws;
    float* knb  = qb  + 32 * 4096;
    float* vnb  = knb + 32 * 1024;
    float* attn = vnb + 32 * 1024;
    float* part = attn + 32 * 4096;
    float* outp = (float*)d_out;

    qkv_mfma<<<384, 512, 0, stream>>>(x, wq, wk, wv, qb, knb, vnb);
    attn_kernel<<<2048, 128, 0, stream>>>(kc, vc, qb, knb, vnb, btab, lens, part);
    combine_kernel<<<256, 256, 0, stream>>>(part, lens, attn);
    wo_mfma<<<256, 512, 0, stream>>>(attn, wo, outp);
}